// Round 10
// baseline (344.174 us; speedup 1.0000x reference)
//
#include <hip/hip_runtime.h>
#include <math.h>

#define NB 8
#define NN 512
#define D 128
#define TIF 4         // query rows per fused block
#define JC 128        // j-chunk size (flash pipeline)
#define NCK (NN / JC) // 4 chunks
#define K1R 8         // rows per k1 block
#define LN_EPS 1e-5f
#define SCALE 0.08838834764831845f  // 1/sqrt(128)

typedef float f32x4 __attribute__((ext_vector_type(4)));

__device__ __forceinline__ float dotv(f32x4 a, f32x4 b) {
    f32x4 m = a * b;
    return m.x + m.y + m.z + m.w;
}
__device__ __forceinline__ float dot4(float4 a, float4 b) {
    return a.x * b.x + a.y * b.y + a.z * b.z + a.w * b.w;
}

// ---------------- Kernel 1: h = x @ W^T, s_i, s_j (unchanged) ---------------
__global__ __launch_bounds__(256) void k1_proj(
    const float* __restrict__ x, const float* __restrict__ W,
    const float* __restrict__ a_src, const float* __restrict__ a_dst,
    float* __restrict__ h_ws, float* __restrict__ si_ws, float* __restrict__ sj_ws)
{
    __shared__ __align__(16) float4 Wl[128][32];   // [o][q ^ (o&7)] swizzle
    __shared__ __align__(16) float4 xl[K1R][32];
    __shared__ float redk[K1R][2][2];

    const int t = threadIdx.x;
    const int row0 = blockIdx.x * K1R;

    const float4* Wg = (const float4*)W;
#pragma unroll
    for (int k = 0; k < 16; ++k) {
        const int f = t + 256 * k;
        const int o = f >> 5, q = f & 31;
        Wl[o][q ^ (o & 7)] = Wg[f];
    }
    xl[t >> 5][t & 31] = ((const float4*)(x + (size_t)row0 * D))[t];
    __syncthreads();

    const int o = t & 127;
    const int rb = (t >> 7) * (K1R / 2);
    float acc[K1R / 2] = {0.f, 0.f, 0.f, 0.f};
#pragma unroll
    for (int q = 0; q < 32; ++q) {
        const float4 wv = Wl[o][q ^ (o & 7)];
#pragma unroll
        for (int r = 0; r < K1R / 2; ++r) acc[r] += dot4(wv, xl[rb + r][q]);
    }
    const float as = a_src[o], ad = a_dst[o];
#pragma unroll
    for (int r = 0; r < K1R / 2; ++r) {
        h_ws[(size_t)(row0 + rb + r) * D + o] = acc[r];
        float vs = acc[r] * as, vd = acc[r] * ad;
#pragma unroll
        for (int m = 32; m >= 1; m >>= 1) {
            vs += __shfl_xor(vs, m);
            vd += __shfl_xor(vd, m);
        }
        if ((t & 63) == 0) {
            redk[rb + r][0][(t >> 6) & 1] = vs;
            redk[rb + r][1][(t >> 6) & 1] = vd;
        }
    }
    __syncthreads();
    if (t < K1R) si_ws[row0 + t] = redk[t][0][0] + redk[t][0][1];
    else if (t < 2 * K1R) {
        const int r = t - K1R;
        sj_ws[row0 + r] = redk[r][1][0] + redk[r][1][1];
    }
}

// ------------- Fused flash kernel: chunked stream + online softmax + PV + LN
// grid: NB * NN / TIF = 1024 blocks, block: 256 (4 waves)
// Per chunk of 128 j: score from prefetched regs, prefetch next chunk,
// online-softmax (m,l,f), rescale + accumulate PV.
__global__ __launch_bounds__(256, 4) void kfused(
    const float* __restrict__ ef, const float* __restrict__ a_e,
    const float* __restrict__ gamma, const float* __restrict__ beta,
    const float* __restrict__ h_ws, const float* __restrict__ si_ws,
    const float* __restrict__ sj_ws, float* __restrict__ out)
{
    __shared__ float sj_l[NN];                         // 2 KB
    __shared__ float sa[TIF][JC];                      // 2 KB raw edge scores
    __shared__ float ab[TIF][JC];                      // 2 KB alpha (chunk)
    __shared__ __align__(16) float part[4][TIF][D];    // 8 KB per-wave PV partials
    __shared__ float redm[TIF][2];
    __shared__ float reds[TIF][2];

    const int t = threadIdx.x;
    const int w = t >> 6;
    const int lane = t & 63;
    const int bid = blockIdx.x;
    const int b = bid >> 7;              // 128 blocks per batch
    const int i0 = (bid & 127) * TIF;

    sj_l[t] = sj_ws[b * NN + t];
    sj_l[t + 256] = sj_ws[b * NN + t + 256];

    float si_r[TIF];
#pragma unroll
    for (int r = 0; r < TIF; ++r) si_r[r] = si_ws[b * NN + i0 + r];

    const int c = t & 3;
    const f32x4 A = ((const f32x4*)a_e)[c];
    const f32x4* ef4 = (const f32x4*)ef + ((size_t)b * NN + i0) * NN * 4;

    // softmax-thread mapping (fixed across chunks)
    const int j = t & 127;               // j within chunk
    const int rp = t >> 7;               // row pair 0..1
    const int r0 = 2 * rp, r1 = 2 * rp + 1;
    const int wh = (t >> 6) & 1;

    // PV-thread mapping
    const int dl = (t & 31) << 2;
    const int g = t >> 5;                // 0..7 (16 j per g per chunk)
    const float* hb = h_ws + (size_t)b * NN * D;

    float m_reg[TIF], l_reg[TIF], fsc[TIF];
    float acc[TIF][4];
#pragma unroll
    for (int r = 0; r < TIF; ++r) {
        m_reg[r] = -1e30f; l_reg[r] = 0.f;
#pragma unroll
        for (int cc = 0; cc < 4; ++cc) acc[r][cc] = 0.f;
    }

    // ---- prefetch chunk 0 into registers (8 x f32x4 per thread)
    f32x4 ldreg[2 * TIF];
#pragma unroll
    for (int r = 0; r < TIF; ++r)
#pragma unroll
        for (int kk = 0; kk < 2; ++kk)
            ldreg[r * 2 + kk] = ef4[r * 2048 + kk * 256 + t];

#pragma unroll
    for (int ck = 0; ck < NCK; ++ck) {
        // ---- stage 1: scores for this chunk from prefetched regs
#pragma unroll
        for (int r = 0; r < TIF; ++r)
#pragma unroll
            for (int kk = 0; kk < 2; ++kk) {
                float p = dotv(ldreg[r * 2 + kk], A);
                p += __shfl_xor(p, 1);
                p += __shfl_xor(p, 2);
                if (c == 0) sa[r][kk * 64 + (t >> 2)] = p;
            }
        // ---- prefetch next chunk (stays in flight across softmax+PV)
        if (ck < NCK - 1) {
#pragma unroll
            for (int r = 0; r < TIF; ++r)
#pragma unroll
                for (int kk = 0; kk < 2; ++kk)
                    ldreg[r * 2 + kk] = ef4[r * 2048 + (ck + 1) * 512 + kk * 256 + t];
        }
        __syncthreads();   // B1: scores visible

        // ---- stage 2: e + chunk max (thread: 1 j, 2 rows)
        const float sjv = sj_l[ck * JC + j];
        const float e0 = (si_r[r0] + sjv + sa[r0][j]) * SCALE;
        const float e1 = (si_r[r1] + sjv + sa[r1][j]) * SCALE;
        float m0 = e0, m1 = e1;
#pragma unroll
        for (int mm = 32; mm >= 1; mm >>= 1) {
            m0 = fmaxf(m0, __shfl_xor(m0, mm));
            m1 = fmaxf(m1, __shfl_xor(m1, mm));
        }
        if (lane == 0) { redm[r0][wh] = m0; redm[r1][wh] = m1; }
        __syncthreads();   // B2: redm visible

        // ---- online max update (uniform across all threads)
#pragma unroll
        for (int r = 0; r < TIF; ++r) {
            const float cm = fmaxf(redm[r][0], redm[r][1]);
            const float mn = fmaxf(m_reg[r], cm);
            fsc[r] = __expf(m_reg[r] - mn);
            m_reg[r] = mn;
        }
        // ---- stage 3: alpha + chunk sums
        {
            const float a0 = __expf(e0 - m_reg[r0]);
            const float a1 = __expf(e1 - m_reg[r1]);
            ab[r0][j] = a0;
            ab[r1][j] = a1;
            float s0 = a0, s1 = a1;
#pragma unroll
            for (int mm = 32; mm >= 1; mm >>= 1) {
                s0 += __shfl_xor(s0, mm);
                s1 += __shfl_xor(s1, mm);
            }
            if (lane == 0) { reds[r0][wh] = s0; reds[r1][wh] = s1; }
        }
        __syncthreads();   // B3: alpha + reds visible

        // ---- l update (uniform)
#pragma unroll
        for (int r = 0; r < TIF; ++r)
            l_reg[r] = l_reg[r] * fsc[r] + reds[r][0] + reds[r][1];

        // ---- stage 4: PV chunk. rescale acc, accumulate 16 j per g.
#pragma unroll
        for (int r = 0; r < TIF; ++r)
#pragma unroll
            for (int cc = 0; cc < 4; ++cc) acc[r][cc] *= fsc[r];

#pragma unroll
        for (int jt = 0; jt < 4; ++jt) {
            const int jl = g * 16 + jt * 4;          // j within chunk
            const int jg = ck * JC + jl;             // global j
            float4 hv0 = *(const float4*)(hb + (size_t)(jg + 0) * D + dl);
            float4 hv1 = *(const float4*)(hb + (size_t)(jg + 1) * D + dl);
            float4 hv2 = *(const float4*)(hb + (size_t)(jg + 2) * D + dl);
            float4 hv3 = *(const float4*)(hb + (size_t)(jg + 3) * D + dl);
#pragma unroll
            for (int r = 0; r < TIF; ++r) {
                const f32x4 av = *(const f32x4*)&ab[r][jl];
                acc[r][0] += av.x * hv0.x + av.y * hv1.x + av.z * hv2.x + av.w * hv3.x;
                acc[r][1] += av.x * hv0.y + av.y * hv1.y + av.z * hv2.y + av.w * hv3.y;
                acc[r][2] += av.x * hv0.z + av.y * hv1.z + av.z * hv2.z + av.w * hv3.z;
                acc[r][3] += av.x * hv0.w + av.y * hv1.w + av.z * hv2.w + av.w * hv3.w;
            }
        }
        __syncthreads();   // B4: ab/sa free for next chunk
    }

    // ---- combine PV partials within wave (g and g^1), write per-wave part
#pragma unroll
    for (int r = 0; r < TIF; ++r)
#pragma unroll
        for (int cc = 0; cc < 4; ++cc) acc[r][cc] += __shfl_xor(acc[r][cc], 32);
    if (lane < 32) {
#pragma unroll
        for (int r = 0; r < TIF; ++r)
            *(float4*)&part[w][r][dl] = make_float4(acc[r][0], acc[r][1], acc[r][2], acc[r][3]);
    }
    __syncthreads();

    // ---- LayerNorm. wave w -> row w; lane -> d, d+64.
    {
        const int r = w;
        const float inv = 1.0f / l_reg[r];
        const int d0 = lane, d1 = lane + 64;
        float v0 = 0.f, v1 = 0.f;
#pragma unroll
        for (int pw = 0; pw < 4; ++pw) {
            v0 += part[pw][r][d0];
            v1 += part[pw][r][d1];
        }
        v0 *= inv; v1 *= inv;
        float s = v0 + v1, qq = v0 * v0 + v1 * v1;
#pragma unroll
        for (int mm = 32; mm >= 1; mm >>= 1) {
            s += __shfl_xor(s, mm);
            qq += __shfl_xor(qq, mm);
        }
        const float mu = s * (1.f / 128.f);
        const float var = qq * (1.f / 128.f) - mu * mu;
        const float rs = rsqrtf(var + LN_EPS);
        const size_t ob = ((size_t)(b * NN + i0 + r)) * D;
        out[ob + d0] = (v0 - mu) * rs * gamma[d0] + beta[d0];
        out[ob + d1] = (v1 - mu) * rs * gamma[d1] + beta[d1];
    }
}

extern "C" void kernel_launch(void* const* d_in, const int* in_sizes, int n_in,
                              void* d_out, int out_size, void* d_ws, size_t ws_size,
                              hipStream_t stream) {
    const float* x     = (const float*)d_in[0];
    const float* ef    = (const float*)d_in[1];
    const float* W     = (const float*)d_in[2];
    const float* a_src = (const float*)d_in[3];
    const float* a_dst = (const float*)d_in[4];
    const float* a_e   = (const float*)d_in[5];
    const float* gamma = (const float*)d_in[6];
    const float* beta  = (const float*)d_in[7];
    float* out = (float*)d_out;

    float* h_ws  = (float*)d_ws;                       // 2 MiB
    float* si_ws = h_ws + (size_t)NB * NN * D;
    float* sj_ws = si_ws + NB * NN;

    k1_proj<<<NB * NN / K1R, 256, 0, stream>>>(x, W, a_src, a_dst, h_ws, si_ws, sj_ws);
    kfused<<<NB * NN / TIF, 256, 0, stream>>>(ef, a_e, gamma, beta,
                                              h_ws, si_ws, sj_ws, out);
}

// Round 11
// 51.455 us; speedup vs baseline: 6.6889x; 6.6889x over previous
//
#include <hip/hip_runtime.h>
#include <math.h>

#define NB 8
#define NN 512
#define D 128
#define TIF 4         // query rows per fused block (= waves per block)
#define JC 64         // j-chunk size (flash pipeline)
#define NCK (NN / JC) // 8 chunks
#define K1R 8         // rows per k1 block
#define LN_EPS 1e-5f
#define SCALE 0.08838834764831845f  // 1/sqrt(128)

typedef float f32x4 __attribute__((ext_vector_type(4)));

__device__ __forceinline__ float dotv(f32x4 a, f32x4 b) {
    f32x4 m = a * b;
    return m.x + m.y + m.z + m.w;
}
__device__ __forceinline__ float dot4(float4 a, float4 b) {
    return a.x * b.x + a.y * b.y + a.z * b.z + a.w * b.w;
}

// ---------------- Kernel 1: h = x @ W^T, s_i, s_j (unchanged) ---------------
__global__ __launch_bounds__(256) void k1_proj(
    const float* __restrict__ x, const float* __restrict__ W,
    const float* __restrict__ a_src, const float* __restrict__ a_dst,
    float* __restrict__ h_ws, float* __restrict__ si_ws, float* __restrict__ sj_ws)
{
    __shared__ __align__(16) float4 Wl[128][32];   // [o][q ^ (o&7)] swizzle
    __shared__ __align__(16) float4 xl[K1R][32];
    __shared__ float redk[K1R][2][2];

    const int t = threadIdx.x;
    const int row0 = blockIdx.x * K1R;

    const float4* Wg = (const float4*)W;
#pragma unroll
    for (int k = 0; k < 16; ++k) {
        const int f = t + 256 * k;
        const int o = f >> 5, q = f & 31;
        Wl[o][q ^ (o & 7)] = Wg[f];
    }
    xl[t >> 5][t & 31] = ((const float4*)(x + (size_t)row0 * D))[t];
    __syncthreads();

    const int o = t & 127;
    const int rb = (t >> 7) * (K1R / 2);
    float acc[K1R / 2] = {0.f, 0.f, 0.f, 0.f};
#pragma unroll
    for (int q = 0; q < 32; ++q) {
        const float4 wv = Wl[o][q ^ (o & 7)];
#pragma unroll
        for (int r = 0; r < K1R / 2; ++r) acc[r] += dot4(wv, xl[rb + r][q]);
    }
    const float as = a_src[o], ad = a_dst[o];
#pragma unroll
    for (int r = 0; r < K1R / 2; ++r) {
        h_ws[(size_t)(row0 + rb + r) * D + o] = acc[r];
        float vs = acc[r] * as, vd = acc[r] * ad;
#pragma unroll
        for (int m = 32; m >= 1; m >>= 1) {
            vs += __shfl_xor(vs, m);
            vd += __shfl_xor(vd, m);
        }
        if ((t & 63) == 0) {
            redk[rb + r][0][(t >> 6) & 1] = vs;
            redk[rb + r][1][(t >> 6) & 1] = vd;
        }
    }
    __syncthreads();
    if (t < K1R) si_ws[row0 + t] = redk[t][0][0] + redk[t][0][1];
    else if (t < 2 * K1R) {
        const int r = t - K1R;
        sj_ws[row0 + r] = redk[r][1][0] + redk[r][1][1];
    }
}

// ------------- Fused flash kernel v2: named regs + raw lgkm-only barriers ---
// grid: 1024 blocks, block: 256 (4 waves). Wave w owns softmax row w.
// Per 64-j chunk: scores from p-regs -> prefetch next chunk (stays in flight,
// barriers never drain vmcnt) -> in-wave online softmax -> PV from L2 h.
__global__ __launch_bounds__(256, 4) void kfused(
    const float* __restrict__ ef, const float* __restrict__ a_e,
    const float* __restrict__ gamma, const float* __restrict__ beta,
    const float* __restrict__ h_ws, const float* __restrict__ si_ws,
    const float* __restrict__ sj_ws, float* __restrict__ out)
{
    __shared__ float sj_l[NN];                        // 2 KB
    __shared__ __align__(16) float sa[TIF][JC];       // 1 KB raw edge scores
    __shared__ __align__(16) float ab[TIF][JC];       // 1 KB alpha chunk
    __shared__ float fsc_l[TIF];
    __shared__ __align__(16) float part[4][TIF][D];   // 8 KB per-wave PV partials

    const int t = threadIdx.x;
    const int w = t >> 6;
    const int lane = t & 63;
    const int bid = blockIdx.x;
    const int b = bid >> 7;              // 128 blocks per batch
    const int i0 = (bid & 127) * TIF;

    sj_l[t] = sj_ws[b * NN + t];
    sj_l[t + 256] = sj_ws[b * NN + t + 256];

    const float si0 = si_ws[b * NN + i0 + 0];
    const float si1 = si_ws[b * NN + i0 + 1];
    const float si2 = si_ws[b * NN + i0 + 2];
    const float si3 = si_ws[b * NN + i0 + 3];
    const float si_w = (t < 64) ? si0 : (t < 128) ? si1 : (t < 192) ? si2 : si3;

    const int c = t & 3;
    const f32x4 A = ((const f32x4*)a_e)[c];
    const f32x4* ef4 = (const f32x4*)ef + ((size_t)b * NN + i0) * NN * 4;

    const int jj = t & 63;               // softmax j (wave-local)
    const int dl = (t & 31) << 2;        // PV d base
    const int g = t >> 5;                // PV j-group 0..7
    const float* hb = h_ws + (size_t)b * NN * D;

    float m_reg = -1e30f, l_reg = 0.f;   // per-wave row state (uniform in wave)
    f32x4 acc0 = {0.f, 0.f, 0.f, 0.f};
    f32x4 acc1 = {0.f, 0.f, 0.f, 0.f};
    f32x4 acc2 = {0.f, 0.f, 0.f, 0.f};
    f32x4 acc3 = {0.f, 0.f, 0.f, 0.f};

    // prefetch chunk 0 (4 named f32x4 regs)
    f32x4 p0 = ef4[0 * 2048 + t];
    f32x4 p1 = ef4[1 * 2048 + t];
    f32x4 p2 = ef4[2 * 2048 + t];
    f32x4 p3 = ef4[3 * 2048 + t];

    for (int ck = 0; ck < NCK; ++ck) {
        // ---- stage 1: scores from p-regs (4-lane reduce over edge quarters)
        {
            float d0 = dotv(p0, A), d1 = dotv(p1, A);
            float d2 = dotv(p2, A), d3 = dotv(p3, A);
            d0 += __shfl_xor(d0, 1); d0 += __shfl_xor(d0, 2);
            d1 += __shfl_xor(d1, 1); d1 += __shfl_xor(d1, 2);
            d2 += __shfl_xor(d2, 1); d2 += __shfl_xor(d2, 2);
            d3 += __shfl_xor(d3, 1); d3 += __shfl_xor(d3, 2);
            if (c == 0) {
                const int jl = t >> 2;
                sa[0][jl] = d0; sa[1][jl] = d1; sa[2][jl] = d2; sa[3][jl] = d3;
            }
        }
        // ---- prefetch next chunk; stays in flight (no vmcnt drain below)
        if (ck < NCK - 1) {
            const int off = (ck + 1) * 256 + t;
            p0 = ef4[0 * 2048 + off];
            p1 = ef4[1 * 2048 + off];
            p2 = ef4[2 * 2048 + off];
            p3 = ef4[3 * 2048 + off];
        }
        asm volatile("s_waitcnt lgkmcnt(0)" ::: "memory");   // B1: sa visible,
        __builtin_amdgcn_s_barrier();                        // ab/fsc free
        __builtin_amdgcn_sched_barrier(0);

        // ---- online softmax: wave w owns row w, all in-wave
        {
            const float e = (si_w + sj_l[ck * JC + jj] + sa[w][jj]) * SCALE;
            float mc = e;
#pragma unroll
            for (int mm = 32; mm >= 1; mm >>= 1) mc = fmaxf(mc, __shfl_xor(mc, mm));
            const float mn = fmaxf(m_reg, mc);
            const float fs = __expf(m_reg - mn);
            m_reg = mn;
            const float av = __expf(e - mn);
            ab[w][jj] = av;
            float ls = av;
#pragma unroll
            for (int mm = 32; mm >= 1; mm >>= 1) ls += __shfl_xor(ls, mm);
            l_reg = l_reg * fs + ls;
            if (lane == 0) fsc_l[w] = fs;
        }
        asm volatile("s_waitcnt lgkmcnt(0)" ::: "memory");   // B2: ab+fsc visible,
        __builtin_amdgcn_s_barrier();                        // sa free
        __builtin_amdgcn_sched_barrier(0);

        // ---- PV: rescale + accumulate 8 j per group from L2-resident h
        {
            const float f0 = fsc_l[0], f1 = fsc_l[1];
            const float f2 = fsc_l[2], f3 = fsc_l[3];
            acc0 *= f0; acc1 *= f1; acc2 *= f2; acc3 *= f3;
#pragma unroll
            for (int jt = 0; jt < 2; ++jt) {
                const int jl = (g << 3) + (jt << 2);
                const int jg = ck * JC + jl;
                const f32x4 hv0 = *(const f32x4*)(hb + (size_t)(jg + 0) * D + dl);
                const f32x4 hv1 = *(const f32x4*)(hb + (size_t)(jg + 1) * D + dl);
                const f32x4 hv2 = *(const f32x4*)(hb + (size_t)(jg + 2) * D + dl);
                const f32x4 hv3 = *(const f32x4*)(hb + (size_t)(jg + 3) * D + dl);
                const f32x4 a0v = *(const f32x4*)&ab[0][jl];
                const f32x4 a1v = *(const f32x4*)&ab[1][jl];
                const f32x4 a2v = *(const f32x4*)&ab[2][jl];
                const f32x4 a3v = *(const f32x4*)&ab[3][jl];
                acc0 += hv0 * a0v.x + hv1 * a0v.y + hv2 * a0v.z + hv3 * a0v.w;
                acc1 += hv0 * a1v.x + hv1 * a1v.y + hv2 * a1v.z + hv3 * a1v.w;
                acc2 += hv0 * a2v.x + hv1 * a2v.y + hv2 * a2v.z + hv3 * a2v.w;
                acc3 += hv0 * a3v.x + hv1 * a3v.y + hv2 * a3v.z + hv3 * a3v.w;
            }
        }
        // next iteration's B1 protects ab/fsc overwrite
    }

    // ---- combine the two j-group halves within each wave
#pragma unroll
    for (int cc = 0; cc < 4; ++cc) {
        acc0[cc] += __shfl_xor(acc0[cc], 32);
        acc1[cc] += __shfl_xor(acc1[cc], 32);
        acc2[cc] += __shfl_xor(acc2[cc], 32);
        acc3[cc] += __shfl_xor(acc3[cc], 32);
    }
    if (lane < 32) {
        *(f32x4*)&part[w][0][dl] = acc0;
        *(f32x4*)&part[w][1][dl] = acc1;
        *(f32x4*)&part[w][2][dl] = acc2;
        *(f32x4*)&part[w][3][dl] = acc3;
    }
    __syncthreads();

    // ---- LayerNorm: wave w -> row w (l_reg is wave w's row denominator)
    {
        const float inv = 1.0f / l_reg;
        const int d0 = lane, d1 = lane + 64;
        float v0 = 0.f, v1 = 0.f;
#pragma unroll
        for (int pw = 0; pw < 4; ++pw) {
            v0 += part[pw][w][d0];
            v1 += part[pw][w][d1];
        }
        v0 *= inv; v1 *= inv;
        float s = v0 + v1, qq = v0 * v0 + v1 * v1;
#pragma unroll
        for (int mm = 32; mm >= 1; mm >>= 1) {
            s += __shfl_xor(s, mm);
            qq += __shfl_xor(qq, mm);
        }
        const float mu = s * (1.f / 128.f);
        const float var = qq * (1.f / 128.f) - mu * mu;
        const float rs = rsqrtf(var + LN_EPS);
        const size_t ob = ((size_t)(b * NN + i0 + w)) * D;
        out[ob + d0] = (v0 - mu) * rs * gamma[d0] + beta[d0];
        out[ob + d1] = (v1 - mu) * rs * gamma[d1] + beta[d1];
    }
}

extern "C" void kernel_launch(void* const* d_in, const int* in_sizes, int n_in,
                              void* d_out, int out_size, void* d_ws, size_t ws_size,
                              hipStream_t stream) {
    const float* x     = (const float*)d_in[0];
    const float* ef    = (const float*)d_in[1];
    const float* W     = (const float*)d_in[2];
    const float* a_src = (const float*)d_in[3];
    const float* a_dst = (const float*)d_in[4];
    const float* a_e   = (const float*)d_in[5];
    const float* gamma = (const float*)d_in[6];
    const float* beta  = (const float*)d_in[7];
    float* out = (float*)d_out;

    float* h_ws  = (float*)d_ws;                       // 2 MiB
    float* si_ws = h_ws + (size_t)NB * NN * D;
    float* sj_ws = si_ws + NB * NN;

    k1_proj<<<NB * NN / K1R, 256, 0, stream>>>(x, W, a_src, a_dst, h_ws, si_ws, sj_ws);
    kfused<<<NB * NN / TIF, 256, 0, stream>>>(ef, a_e, gamma, beta,
                                              h_ws, si_ws, sj_ws, out);
}